// Round 1
// baseline (3459.298 us; speedup 1.0000x reference)
//
#include <hip/hip_runtime.h>

#define DIAGNUM 50000
#define MEDNUM  20000
#define PRONUM  40000
#define FEATDIM 128
#define N1 (DIAGNUM + MEDNUM)   // 70000
#define N2 (PRONUM + MEDNUM)    // 60000
#define NNZ1 1120000
#define NNZ2 960000

// One 64-lane wave per edge. Each lane handles 2 consecutive feature floats.
// acc[row] += val * x[col], where x = concat(xlo[0:nlo], xhi[...]).
__global__ void spmm_atomic_kernel(const int* __restrict__ rows,
                                   const int* __restrict__ cols,
                                   const float* __restrict__ vals,
                                   const float* __restrict__ xlo,
                                   const float* __restrict__ xhi,
                                   int nlo,
                                   float* __restrict__ acc,
                                   int nnz) {
    int gtid = blockIdx.x * blockDim.x + threadIdx.x;
    int e    = gtid >> 6;          // wave id = edge id
    int lane = gtid & 63;
    if (e >= nnz) return;

    int   r = rows[e];
    int   c = cols[e];
    float v = vals[e];

    const float* xb = (c < nlo) ? (xlo + (size_t)c * FEATDIM)
                                : (xhi + (size_t)(c - nlo) * FEATDIM);
    float2 x2 = reinterpret_cast<const float2*>(xb)[lane];

    float* dst = acc + (size_t)r * FEATDIM + lane * 2;
    atomicAdd(dst,     v * x2.x);
    atomicAdd(dst + 1, v * x2.y);
}

// v = 2*relu(acc); rows < nlo go to dst_lo (contiguous), rows >= nlo to dst_hi.
// add==1: accumulate into destination (second adjacency of the pair).
__global__ void relu2_store_kernel(const float* __restrict__ acc,
                                   float* __restrict__ dst_lo,
                                   float* __restrict__ dst_hi,
                                   long nlo_elems, long total_elems, int add) {
    long i = ((long)blockIdx.x * blockDim.x + threadIdx.x) * 4;
    if (i >= total_elems) return;

    float4 a = *reinterpret_cast<const float4*>(acc + i);
    float4 v;
    v.x = 2.0f * fmaxf(a.x, 0.0f);
    v.y = 2.0f * fmaxf(a.y, 0.0f);
    v.z = 2.0f * fmaxf(a.z, 0.0f);
    v.w = 2.0f * fmaxf(a.w, 0.0f);

    float* base = (i < nlo_elems) ? dst_lo : (dst_hi - nlo_elems);
    float4* d = reinterpret_cast<float4*>(base + i);
    if (add) {
        float4 o = *d;
        v.x += o.x; v.y += o.y; v.z += o.z; v.w += o.w;
    }
    *d = v;
}

// out_m = t*g1med + (1-t)*g2med
__global__ void combine_med_kernel(const float* __restrict__ g1med,
                                   const float* __restrict__ g2med,
                                   const float* __restrict__ inter,
                                   float* __restrict__ outm,
                                   long total_elems) {
    long i = ((long)blockIdx.x * blockDim.x + threadIdx.x) * 4;
    if (i >= total_elems) return;
    float t = *inter;
    float4 a = *reinterpret_cast<const float4*>(g1med + i);
    float4 b = *reinterpret_cast<const float4*>(g2med + i);
    float4 v;
    v.x = t * a.x + (1.0f - t) * b.x;
    v.y = t * a.y + (1.0f - t) * b.y;
    v.z = t * a.z + (1.0f - t) * b.z;
    v.w = t * a.w + (1.0f - t) * b.w;
    *reinterpret_cast<float4*>(outm + i) = v;
}

extern "C" void kernel_launch(void* const* d_in, const int* in_sizes, int n_in,
                              void* d_out, int out_size, void* d_ws, size_t ws_size,
                              hipStream_t stream) {
    const int*   a1r = (const int*)d_in[0];
    const int*   a1c = (const int*)d_in[1];
    const float* a1v = (const float*)d_in[2];
    const int*   a2r = (const int*)d_in[3];
    const int*   a2c = (const int*)d_in[4];
    const float* a2v = (const float*)d_in[5];
    const float* dE  = (const float*)d_in[6];
    const float* mE  = (const float*)d_in[7];
    const float* pE  = (const float*)d_in[8];
    const float* inter = (const float*)d_in[9];

    float* out   = (float*)d_out;
    float* out_m = out;                                    // 20000*128
    float* out_d = out + (size_t)MEDNUM * FEATDIM;         // 50000*128
    float* out_p = out_d + (size_t)DIAGNUM * FEATDIM;      // 40000*128

    float* acc   = (float*)d_ws;                           // 70000*128 f32
    float* g1med = acc + (size_t)N1 * FEATDIM;             // 20000*128
    float* g2med = g1med + (size_t)MEDNUM * FEATDIM;       // 20000*128

    const int BLK = 256;
    // SpMM grids: one wave (64 threads) per edge
    int grid_s1 = (int)(((long)NNZ1 * 64 + BLK - 1) / BLK);
    int grid_s2 = (int)(((long)NNZ2 * 64 + BLK - 1) / BLK);
    // Store grids: float4 per thread
    long tot1 = (long)N1 * FEATDIM;
    long tot2 = (long)N2 * FEATDIM;
    long totm = (long)MEDNUM * FEATDIM;
    int grid_r1 = (int)((tot1 / 4 + BLK - 1) / BLK);
    int grid_r2 = (int)((tot2 / 4 + BLK - 1) / BLK);
    int grid_cm = (int)((totm / 4 + BLK - 1) / BLK);

    // ---- graph 1 (e1 = [dEmbed; mEmbed], N1 rows) ----
    hipMemsetAsync(acc, 0, (size_t)tot1 * sizeof(float), stream);
    spmm_atomic_kernel<<<grid_s1, BLK, 0, stream>>>(a1r, a1c, a1v, dE, mE, DIAGNUM, acc, NNZ1);
    relu2_store_kernel<<<grid_r1, BLK, 0, stream>>>(acc, out_d, g1med,
                                                    (long)DIAGNUM * FEATDIM, tot1, 0);
    hipMemsetAsync(acc, 0, (size_t)tot1 * sizeof(float), stream);
    spmm_atomic_kernel<<<grid_s1, BLK, 0, stream>>>(a1r + NNZ1, a1c + NNZ1, a1v + NNZ1,
                                                    dE, mE, DIAGNUM, acc, NNZ1);
    relu2_store_kernel<<<grid_r1, BLK, 0, stream>>>(acc, out_d, g1med,
                                                    (long)DIAGNUM * FEATDIM, tot1, 1);

    // ---- graph 2 (e2 = [pEmbed; mEmbed], N2 rows) ----
    hipMemsetAsync(acc, 0, (size_t)tot2 * sizeof(float), stream);
    spmm_atomic_kernel<<<grid_s2, BLK, 0, stream>>>(a2r, a2c, a2v, pE, mE, PRONUM, acc, NNZ2);
    relu2_store_kernel<<<grid_r2, BLK, 0, stream>>>(acc, out_p, g2med,
                                                    (long)PRONUM * FEATDIM, tot2, 0);
    hipMemsetAsync(acc, 0, (size_t)tot2 * sizeof(float), stream);
    spmm_atomic_kernel<<<grid_s2, BLK, 0, stream>>>(a2r + NNZ2, a2c + NNZ2, a2v + NNZ2,
                                                    pE, mE, PRONUM, acc, NNZ2);
    relu2_store_kernel<<<grid_r2, BLK, 0, stream>>>(acc, out_p, g2med,
                                                    (long)PRONUM * FEATDIM, tot2, 1);

    // ---- final med combine ----
    combine_med_kernel<<<grid_cm, BLK, 0, stream>>>(g1med, g2med, inter, out_m, totm);
}

// Round 2
// 814.169 us; speedup vs baseline: 4.2489x; 4.2489x over previous
//
#include <hip/hip_runtime.h>

#define DIAGNUM 50000
#define MEDNUM  20000
#define PRONUM  40000
#define FEATDIM 128
#define N1 (DIAGNUM + MEDNUM)   // 70000
#define N2 (PRONUM + MEDNUM)    // 60000
#define NNZ1 1120000
#define NNZ2 960000

// ---------------- CSR construction ----------------

__global__ void hist_kernel(const int* __restrict__ rows, int nnz,
                            int* __restrict__ counts) {
    int i = blockIdx.x * blockDim.x + threadIdx.x;
    if (i < nnz) atomicAdd(&counts[rows[i]], 1);
}

// chunk = 1024 elems per block (256 threads x 4)
__global__ void scan_reduce_kernel(const int* __restrict__ counts, int n,
                                   int* __restrict__ partials) {
    __shared__ int s[256];
    int t = threadIdx.x;
    int base = blockIdx.x * 1024 + t * 4;
    int sum = 0;
#pragma unroll
    for (int k = 0; k < 4; k++) {
        int idx = base + k;
        if (idx < n) sum += counts[idx];
    }
    s[t] = sum;
    __syncthreads();
    for (int off = 128; off > 0; off >>= 1) {
        if (t < off) s[t] += s[t + off];
        __syncthreads();
    }
    if (t == 0) partials[blockIdx.x] = s[0];
}

// single block: exclusive scan of partials[nchunks] (nchunks <= 256), in place
__global__ void scan_mid_kernel(int* __restrict__ partials, int nchunks) {
    __shared__ int s[256];
    int t = threadIdx.x;
    int v = (t < nchunks) ? partials[t] : 0;
    s[t] = v;
    __syncthreads();
    for (int off = 1; off < 256; off <<= 1) {
        int y = (t >= off) ? s[t - off] : 0;
        __syncthreads();
        s[t] += y;
        __syncthreads();
    }
    if (t < nchunks) partials[t] = s[t] - v;
}

// in-place: counts[i] -> exclusive prefix (start offset of row i)
__global__ void scan_apply_kernel(int* __restrict__ counts, int n,
                                  const int* __restrict__ partials) {
    __shared__ int s[256];
    int t = threadIdx.x;
    int base = blockIdx.x * 1024 + t * 4;
    int v[4];
    int sum = 0;
#pragma unroll
    for (int k = 0; k < 4; k++) {
        int idx = base + k;
        v[k] = (idx < n) ? counts[idx] : 0;
        sum += v[k];
    }
    s[t] = sum;
    __syncthreads();
    for (int off = 1; off < 256; off <<= 1) {
        int y = (t >= off) ? s[t - off] : 0;
        __syncthreads();
        s[t] += y;
        __syncthreads();
    }
    int excl = s[t] - sum;
    int run = partials[blockIdx.x] + excl;
#pragma unroll
    for (int k = 0; k < 4; k++) {
        int idx = base + k;
        if (idx < n) {
            counts[idx] = run;
            run += v[k];
        }
    }
}

// cursor = rowptr (start offsets); after this kernel cursor[r] == end offset of
// row r, so row r spans [r ? cursor[r-1] : 0, cursor[r])
__global__ void scatter_kernel(const int* __restrict__ rows,
                               const int* __restrict__ cols,
                               const float* __restrict__ vals, int nnz,
                               int* __restrict__ cursor,
                               int2* __restrict__ edges) {
    int i = blockIdx.x * blockDim.x + threadIdx.x;
    if (i < nnz) {
        int pos = atomicAdd(&cursor[rows[i]], 1);
        edges[pos] = make_int2(cols[i], __float_as_int(vals[i]));
    }
}

// ---------------- fused GCN row kernel ----------------

__device__ __forceinline__ float2 row_sum(const int* __restrict__ rowptr,
                                          const int2* __restrict__ edges,
                                          int r, int lane,
                                          const float* __restrict__ xlo,
                                          const float* __restrict__ xhi,
                                          int nlo) {
    int s = (r == 0) ? 0 : rowptr[r - 1];
    int e = rowptr[r];
    float2 acc = make_float2(0.f, 0.f);
    for (int j = s; j < e; j += 64) {
        int chunk = min(64, e - j);
        int2 ed = (lane < chunk) ? edges[j + lane] : make_int2(0, 0);
        for (int k = 0; k < chunk; k++) {
            int   c = __shfl(ed.x, k);
            float v = __int_as_float(__shfl(ed.y, k));
            const float* xb = (c < nlo) ? xlo + (size_t)c * FEATDIM
                                        : xhi + (size_t)(c - nlo) * FEATDIM;
            float2 x2 = reinterpret_cast<const float2*>(xb)[lane];
            acc.x += v * x2.x;
            acc.y += v * x2.y;
        }
    }
    return acc;
}

// one 64-lane wave per row; out = 2*(relu(A0*x) + relu(A1*x)), routed
__global__ void fused_gcn_kernel(const int* __restrict__ rpA,
                                 const int2* __restrict__ edgA,
                                 const int* __restrict__ rpB,
                                 const int2* __restrict__ edgB,
                                 const float* __restrict__ xlo,
                                 const float* __restrict__ xhi, int nlo,
                                 float* __restrict__ dst_lo,
                                 float* __restrict__ dst_hi, int n) {
    int gtid = blockIdx.x * blockDim.x + threadIdx.x;
    int r = gtid >> 6;
    int lane = gtid & 63;
    if (r >= n) return;

    float2 sA = row_sum(rpA, edgA, r, lane, xlo, xhi, nlo);
    float2 sB = row_sum(rpB, edgB, r, lane, xlo, xhi, nlo);

    float2 res;
    res.x = 2.0f * (fmaxf(sA.x, 0.f) + fmaxf(sB.x, 0.f));
    res.y = 2.0f * (fmaxf(sA.y, 0.f) + fmaxf(sB.y, 0.f));

    float* dst = (r < nlo) ? dst_lo + (size_t)r * FEATDIM
                           : dst_hi + (size_t)(r - nlo) * FEATDIM;
    reinterpret_cast<float2*>(dst)[lane] = res;
}

// out_m = t*g1med + (1-t)*g2med
__global__ void combine_med_kernel(const float* __restrict__ g1med,
                                   const float* __restrict__ g2med,
                                   const float* __restrict__ inter,
                                   float* __restrict__ outm, long total_elems) {
    long i = ((long)blockIdx.x * blockDim.x + threadIdx.x) * 4;
    if (i >= total_elems) return;
    float t = *inter;
    float4 a = *reinterpret_cast<const float4*>(g1med + i);
    float4 b = *reinterpret_cast<const float4*>(g2med + i);
    float4 v;
    v.x = t * a.x + (1.0f - t) * b.x;
    v.y = t * a.y + (1.0f - t) * b.y;
    v.z = t * a.z + (1.0f - t) * b.z;
    v.w = t * a.w + (1.0f - t) * b.w;
    *reinterpret_cast<float4*>(outm + i) = v;
}

// ---------------- host orchestration ----------------

static inline void build_csr(const int* rows, const int* cols, const float* vals,
                             int nnz, int n, int* rowptr, int2* edges,
                             int* partials, hipStream_t stream) {
    const int BLK = 256;
    int nchunks = (n + 1023) / 1024;
    hipMemsetAsync(rowptr, 0, (size_t)n * sizeof(int), stream);
    hist_kernel<<<(nnz + BLK - 1) / BLK, BLK, 0, stream>>>(rows, nnz, rowptr);
    scan_reduce_kernel<<<nchunks, BLK, 0, stream>>>(rowptr, n, partials);
    scan_mid_kernel<<<1, BLK, 0, stream>>>(partials, nchunks);
    scan_apply_kernel<<<nchunks, BLK, 0, stream>>>(rowptr, n, partials);
    scatter_kernel<<<(nnz + BLK - 1) / BLK, BLK, 0, stream>>>(rows, cols, vals,
                                                              nnz, rowptr, edges);
}

extern "C" void kernel_launch(void* const* d_in, const int* in_sizes, int n_in,
                              void* d_out, int out_size, void* d_ws, size_t ws_size,
                              hipStream_t stream) {
    const int*   a1r = (const int*)d_in[0];
    const int*   a1c = (const int*)d_in[1];
    const float* a1v = (const float*)d_in[2];
    const int*   a2r = (const int*)d_in[3];
    const int*   a2c = (const int*)d_in[4];
    const float* a2v = (const float*)d_in[5];
    const float* dE  = (const float*)d_in[6];
    const float* mE  = (const float*)d_in[7];
    const float* pE  = (const float*)d_in[8];
    const float* inter = (const float*)d_in[9];

    float* out   = (float*)d_out;
    float* out_m = out;                               // 20000*128
    float* out_d = out + (size_t)MEDNUM * FEATDIM;    // 50000*128
    float* out_p = out_d + (size_t)DIAGNUM * FEATDIM; // 40000*128

    // ws layout (8-byte aligned blocks first)
    char* ws = (char*)d_ws;
    float* g1med = (float*)ws;                               ws += (size_t)MEDNUM * FEATDIM * 4;  // 10.24 MB
    float* g2med = (float*)ws;                               ws += (size_t)MEDNUM * FEATDIM * 4;  // 10.24 MB
    int2*  e1a   = (int2*)ws;                                ws += (size_t)NNZ1 * 8;
    int2*  e1b   = (int2*)ws;                                ws += (size_t)NNZ1 * 8;
    int2*  e2a   = (int2*)ws;                                ws += (size_t)NNZ2 * 8;
    int2*  e2b   = (int2*)ws;                                ws += (size_t)NNZ2 * 8;
    int*   rp1a  = (int*)ws;                                 ws += (size_t)N1 * 4;
    int*   rp1b  = (int*)ws;                                 ws += (size_t)N1 * 4;
    int*   rp2a  = (int*)ws;                                 ws += (size_t)N2 * 4;
    int*   rp2b  = (int*)ws;                                 ws += (size_t)N2 * 4;
    int*   partials = (int*)ws;                              ws += 256 * 4;

    // build 4 CSRs
    build_csr(a1r,        a1c,        a1v,        NNZ1, N1, rp1a, e1a, partials, stream);
    build_csr(a1r + NNZ1, a1c + NNZ1, a1v + NNZ1, NNZ1, N1, rp1b, e1b, partials, stream);
    build_csr(a2r,        a2c,        a2v,        NNZ2, N2, rp2a, e2a, partials, stream);
    build_csr(a2r + NNZ2, a2c + NNZ2, a2v + NNZ2, NNZ2, N2, rp2b, e2b, partials, stream);

    const int BLK = 256;
    // fused GCN: one wave per row, 4 rows per block
    fused_gcn_kernel<<<N1 / 4, BLK, 0, stream>>>(rp1a, e1a, rp1b, e1b,
                                                 dE, mE, DIAGNUM,
                                                 out_d, g1med, N1);
    fused_gcn_kernel<<<N2 / 4, BLK, 0, stream>>>(rp2a, e2a, rp2b, e2b,
                                                 pE, mE, PRONUM,
                                                 out_p, g2med, N2);

    long totm = (long)MEDNUM * FEATDIM;
    combine_med_kernel<<<(int)((totm / 4 + BLK - 1) / BLK), BLK, 0, stream>>>(
        g1med, g2med, inter, out_m, totm);
}

// Round 3
// 776.239 us; speedup vs baseline: 4.4565x; 1.0489x over previous
//
#include <hip/hip_runtime.h>

#define DIAGNUM 50000
#define MEDNUM  20000
#define PRONUM  40000
#define FEATDIM 128
#define N1 (DIAGNUM + MEDNUM)   // 70000
#define N2 (PRONUM + MEDNUM)    // 60000
#define NNZ1 1120000
#define NNZ2 960000
#define NTOT (2 * N1 + 2 * N2)            // 260000 concatenated rows
#define NNZTOT (2 * NNZ1 + 2 * NNZ2)      // 4160000 concatenated edges

// ---------------- fused CSR construction (all 4 adjacencies) ----------------

// counts = rpe+1, concatenated per-CSR row counts
__global__ void hist4_kernel(const int* __restrict__ a1r,
                             const int* __restrict__ a2r,
                             int* __restrict__ counts) {
    int i = blockIdx.x * blockDim.x + threadIdx.x;
    if (i >= NNZTOT) return;
    int idx;
    if (i < 2 * NNZ1) {
        idx = ((i < NNZ1) ? 0 : N1) + a1r[i];
    } else {
        int j = i - 2 * NNZ1;
        idx = 2 * N1 + ((j < NNZ2) ? 0 : N2) + a2r[j];
    }
    atomicAdd(&counts[idx], 1);
}

// chunk = 1024 elems per block (256 threads x 4)
__global__ void scan_reduce_kernel(const int* __restrict__ counts, int n,
                                   int* __restrict__ partials) {
    __shared__ int s[256];
    int t = threadIdx.x;
    int base = blockIdx.x * 1024 + t * 4;
    int sum = 0;
#pragma unroll
    for (int k = 0; k < 4; k++) {
        int idx = base + k;
        if (idx < n) sum += counts[idx];
    }
    s[t] = sum;
    __syncthreads();
    for (int off = 128; off > 0; off >>= 1) {
        if (t < off) s[t] += s[t + off];
        __syncthreads();
    }
    if (t == 0) partials[blockIdx.x] = s[0];
}

// single block: exclusive scan of partials[nchunks] (nchunks <= 256), in place
__global__ void scan_mid_kernel(int* __restrict__ partials, int nchunks) {
    __shared__ int s[256];
    int t = threadIdx.x;
    int v = (t < nchunks) ? partials[t] : 0;
    s[t] = v;
    __syncthreads();
    for (int off = 1; off < 256; off <<= 1) {
        int y = (t >= off) ? s[t - off] : 0;
        __syncthreads();
        s[t] += y;
        __syncthreads();
    }
    if (t < nchunks) partials[t] = s[t] - v;
}

// in-place: counts[i] -> exclusive prefix (start offset of row i)
__global__ void scan_apply_kernel(int* __restrict__ counts, int n,
                                  const int* __restrict__ partials) {
    __shared__ int s[256];
    int t = threadIdx.x;
    int base = blockIdx.x * 1024 + t * 4;
    int v[4];
    int sum = 0;
#pragma unroll
    for (int k = 0; k < 4; k++) {
        int idx = base + k;
        v[k] = (idx < n) ? counts[idx] : 0;
        sum += v[k];
    }
    s[t] = sum;
    __syncthreads();
    for (int off = 1; off < 256; off <<= 1) {
        int y = (t >= off) ? s[t - off] : 0;
        __syncthreads();
        s[t] += y;
        __syncthreads();
    }
    int excl = s[t] - sum;
    int run = partials[blockIdx.x] + excl;
#pragma unroll
    for (int k = 0; k < 4; k++) {
        int idx = base + k;
        if (idx < n) {
            counts[idx] = run;
            run += v[k];
        }
    }
}

// cursor = rpe+1 (start offsets). After this kernel rpe[1+i] == end offset of
// concatenated row i, so row i spans [rpe[i], rpe[i+1]) (rpe[0] == 0).
__global__ void scatter4_kernel(const int* __restrict__ a1r,
                                const int* __restrict__ a1c,
                                const float* __restrict__ a1v,
                                const int* __restrict__ a2r,
                                const int* __restrict__ a2c,
                                const float* __restrict__ a2v,
                                int* __restrict__ cursor,
                                int2* __restrict__ edges) {
    int i = blockIdx.x * blockDim.x + threadIdx.x;
    if (i >= NNZTOT) return;
    int idx, col;
    float val;
    if (i < 2 * NNZ1) {
        idx = ((i < NNZ1) ? 0 : N1) + a1r[i];
        col = a1c[i];
        val = a1v[i];
    } else {
        int j = i - 2 * NNZ1;
        idx = 2 * N1 + ((j < NNZ2) ? 0 : N2) + a2r[j];
        col = a2c[j];
        val = a2v[j];
    }
    int pos = atomicAdd(&cursor[idx], 1);
    edges[pos] = make_int2(col, __float_as_int(val));
}

// ---------------- fused GCN row kernel ----------------
// Half-wave scheme: 2 edges per iteration, 32 lanes x float4 per edge.

__device__ __forceinline__ float4 row_gather(const int* __restrict__ rp,
                                             const int2* __restrict__ edges,
                                             int lane, int half, int sub,
                                             const float* __restrict__ xlo,
                                             const float* __restrict__ xhi,
                                             int nlo) {
    int s = rp[0];
    int e = rp[1];
    float4 acc = make_float4(0.f, 0.f, 0.f, 0.f);
    for (int j = s; j < e; j += 64) {
        int chunk = min(64, e - j);
        int2 ed = (lane < chunk) ? edges[j + lane] : make_int2(0, 0);
        for (int k = 0; k < chunk; k += 2) {
            // idx may equal chunk on odd tails: that lane holds {0,0} -> v=0
            int   c = __shfl(ed.x, k + half);
            float v = __int_as_float(__shfl(ed.y, k + half));
            const float* xb = (c < nlo) ? xlo + (size_t)c * FEATDIM
                                        : xhi + (size_t)(c - nlo) * FEATDIM;
            float4 x4 = reinterpret_cast<const float4*>(xb)[sub];
            acc.x += v * x4.x;
            acc.y += v * x4.y;
            acc.z += v * x4.z;
            acc.w += v * x4.w;
        }
    }
    return acc;
}

// one 64-lane wave per output row across BOTH graphs
__global__ __launch_bounds__(256) void fused_gcn2_kernel(
        const int* __restrict__ rpe,       // concatenated rowptr_ext
        const int2* __restrict__ edges,    // concatenated edge buffer
        const float* __restrict__ dE, const float* __restrict__ mE,
        const float* __restrict__ pE,
        float* __restrict__ out_d, float* __restrict__ g1med,
        float* __restrict__ out_p, float* __restrict__ g2med) {
    int gtid = blockIdx.x * blockDim.x + threadIdx.x;
    int w    = gtid >> 6;
    int lane = gtid & 63;
    int half = lane >> 5;
    int sub  = lane & 31;
    if (w >= N1 + N2) return;

    const float *xlo, *xhi;
    const int *rpA, *rpB;
    float* dst;
    int nlo;
    if (w < N1) {
        xlo = dE; xhi = mE; nlo = DIAGNUM;
        rpA = rpe + w;
        rpB = rpe + N1 + w;
        dst = (w < DIAGNUM) ? out_d + (size_t)w * FEATDIM
                            : g1med + (size_t)(w - DIAGNUM) * FEATDIM;
    } else {
        int r = w - N1;
        xlo = pE; xhi = mE; nlo = PRONUM;
        rpA = rpe + 2 * N1 + r;
        rpB = rpe + 2 * N1 + N2 + r;
        dst = (r < PRONUM) ? out_p + (size_t)r * FEATDIM
                           : g2med + (size_t)(r - PRONUM) * FEATDIM;
    }

    float4 sA = row_gather(rpA, edges, lane, half, sub, xlo, xhi, nlo);
    float4 sB = row_gather(rpB, edges, lane, half, sub, xlo, xhi, nlo);

    float4 res;
    res.x = 2.f * (fmaxf(sA.x + __shfl_xor(sA.x, 32), 0.f) +
                   fmaxf(sB.x + __shfl_xor(sB.x, 32), 0.f));
    res.y = 2.f * (fmaxf(sA.y + __shfl_xor(sA.y, 32), 0.f) +
                   fmaxf(sB.y + __shfl_xor(sB.y, 32), 0.f));
    res.z = 2.f * (fmaxf(sA.z + __shfl_xor(sA.z, 32), 0.f) +
                   fmaxf(sB.z + __shfl_xor(sB.z, 32), 0.f));
    res.w = 2.f * (fmaxf(sA.w + __shfl_xor(sA.w, 32), 0.f) +
                   fmaxf(sB.w + __shfl_xor(sB.w, 32), 0.f));

    if (half == 0) {
        reinterpret_cast<float4*>(dst)[sub] = res;
    }
}

// out_m = t*g1med + (1-t)*g2med
__global__ void combine_med_kernel(const float* __restrict__ g1med,
                                   const float* __restrict__ g2med,
                                   const float* __restrict__ inter,
                                   float* __restrict__ outm, long total_elems) {
    long i = ((long)blockIdx.x * blockDim.x + threadIdx.x) * 4;
    if (i >= total_elems) return;
    float t = *inter;
    float4 a = *reinterpret_cast<const float4*>(g1med + i);
    float4 b = *reinterpret_cast<const float4*>(g2med + i);
    float4 v;
    v.x = t * a.x + (1.0f - t) * b.x;
    v.y = t * a.y + (1.0f - t) * b.y;
    v.z = t * a.z + (1.0f - t) * b.z;
    v.w = t * a.w + (1.0f - t) * b.w;
    *reinterpret_cast<float4*>(outm + i) = v;
}

// ---------------- host orchestration ----------------

extern "C" void kernel_launch(void* const* d_in, const int* in_sizes, int n_in,
                              void* d_out, int out_size, void* d_ws, size_t ws_size,
                              hipStream_t stream) {
    const int*   a1r = (const int*)d_in[0];
    const int*   a1c = (const int*)d_in[1];
    const float* a1v = (const float*)d_in[2];
    const int*   a2r = (const int*)d_in[3];
    const int*   a2c = (const int*)d_in[4];
    const float* a2v = (const float*)d_in[5];
    const float* dE  = (const float*)d_in[6];
    const float* mE  = (const float*)d_in[7];
    const float* pE  = (const float*)d_in[8];
    const float* inter = (const float*)d_in[9];

    float* out   = (float*)d_out;
    float* out_m = out;                               // 20000*128
    float* out_d = out + (size_t)MEDNUM * FEATDIM;    // 50000*128
    float* out_p = out_d + (size_t)DIAGNUM * FEATDIM; // 40000*128

    // ws layout
    char* ws = (char*)d_ws;
    float* g1med = (float*)ws;      ws += (size_t)MEDNUM * FEATDIM * 4;   // 10.24 MB
    float* g2med = (float*)ws;      ws += (size_t)MEDNUM * FEATDIM * 4;   // 10.24 MB
    int2*  edges = (int2*)ws;       ws += (size_t)NNZTOT * 8;             // 33.28 MB
    int*   rpe   = (int*)ws;        ws += (size_t)(NTOT + 1) * 4;         // 1.04 MB
    int*   partials = (int*)ws;     ws += 256 * 4;

    const int BLK = 256;
    int nchunks = (NTOT + 1023) / 1024;   // 254

    // rpe[0] = 0, counts (rpe+1) = 0
    hipMemsetAsync(rpe, 0, (size_t)(NTOT + 1) * sizeof(int), stream);
    hist4_kernel<<<(NNZTOT + BLK - 1) / BLK, BLK, 0, stream>>>(a1r, a2r, rpe + 1);
    scan_reduce_kernel<<<nchunks, BLK, 0, stream>>>(rpe + 1, NTOT, partials);
    scan_mid_kernel<<<1, BLK, 0, stream>>>(partials, nchunks);
    scan_apply_kernel<<<nchunks, BLK, 0, stream>>>(rpe + 1, NTOT, partials);
    scatter4_kernel<<<(NNZTOT + BLK - 1) / BLK, BLK, 0, stream>>>(
        a1r, a1c, a1v, a2r, a2c, a2v, rpe + 1, edges);

    // fused GCN over both graphs: one wave per row, 4 rows per block
    int nrows = N1 + N2;   // 130000
    fused_gcn2_kernel<<<(nrows + 3) / 4, BLK, 0, stream>>>(
        rpe, edges, dE, mE, pE, out_d, g1med, out_p, g2med);

    long totm = (long)MEDNUM * FEATDIM;
    combine_med_kernel<<<(int)((totm / 4 + BLK - 1) / BLK), BLK, 0, stream>>>(
        g1med, g2med, inter, out_m, totm);
}

// Round 4
// 705.852 us; speedup vs baseline: 4.9009x; 1.0997x over previous
//
#include <hip/hip_runtime.h>

#define DIAGNUM 50000
#define MEDNUM  20000
#define PRONUM  40000
#define FEATDIM 128
#define N1 (DIAGNUM + MEDNUM)   // 70000
#define N2 (PRONUM + MEDNUM)    // 60000
#define NNZ1 1120000
#define NNZ2 960000
#define NTOT (2 * N1 + 2 * N2)            // 260000 concatenated rows
#define NNZTOT (2 * NNZ1 + 2 * NNZ2)      // 4160000 concatenated edges
#define NSLICE 16                          // destination slices (2 XCD passes x 8)
#define SC_CHUNK 2048                      // edges per scatter block

// ---------------- fused CSR construction (all 4 adjacencies) ----------------

// counts = rpe+1, concatenated per-CSR row counts
__global__ void hist4_kernel(const int* __restrict__ a1r,
                             const int* __restrict__ a2r,
                             int* __restrict__ counts) {
    int i = blockIdx.x * blockDim.x + threadIdx.x;
    if (i >= NNZTOT) return;
    int idx;
    if (i < 2 * NNZ1) {
        idx = ((i < NNZ1) ? 0 : N1) + __builtin_nontemporal_load(a1r + i);
    } else {
        int j = i - 2 * NNZ1;
        idx = 2 * N1 + ((j < NNZ2) ? 0 : N2) + __builtin_nontemporal_load(a2r + j);
    }
    atomicAdd(&counts[idx], 1);
}

// chunk = 1024 elems per block (256 threads x 4)
__global__ void scan_reduce_kernel(const int* __restrict__ counts, int n,
                                   int* __restrict__ partials) {
    __shared__ int s[256];
    int t = threadIdx.x;
    int base = blockIdx.x * 1024 + t * 4;
    int sum = 0;
#pragma unroll
    for (int k = 0; k < 4; k++) {
        int idx = base + k;
        if (idx < n) sum += counts[idx];
    }
    s[t] = sum;
    __syncthreads();
    for (int off = 128; off > 0; off >>= 1) {
        if (t < off) s[t] += s[t + off];
        __syncthreads();
    }
    if (t == 0) partials[blockIdx.x] = s[0];
}

// single block: exclusive scan of partials[nchunks] (nchunks <= 256), in place
__global__ void scan_mid_kernel(int* __restrict__ partials, int nchunks) {
    __shared__ int s[256];
    int t = threadIdx.x;
    int v = (t < nchunks) ? partials[t] : 0;
    s[t] = v;
    __syncthreads();
    for (int off = 1; off < 256; off <<= 1) {
        int y = (t >= off) ? s[t - off] : 0;
        __syncthreads();
        s[t] += y;
        __syncthreads();
    }
    if (t < nchunks) partials[t] = s[t] - v;
}

// in-place: counts[i] -> exclusive prefix (start offset of row i)
__global__ void scan_apply_kernel(int* __restrict__ counts, int n,
                                  const int* __restrict__ partials) {
    __shared__ int s[256];
    int t = threadIdx.x;
    int base = blockIdx.x * 1024 + t * 4;
    int v[4];
    int sum = 0;
#pragma unroll
    for (int k = 0; k < 4; k++) {
        int idx = base + k;
        v[k] = (idx < n) ? counts[idx] : 0;
        sum += v[k];
    }
    s[t] = sum;
    __syncthreads();
    for (int off = 1; off < 256; off <<= 1) {
        int y = (t >= off) ? s[t - off] : 0;
        __syncthreads();
        s[t] += y;
        __syncthreads();
    }
    int excl = s[t] - sum;
    int run = partials[blockIdx.x] + excl;
#pragma unroll
    for (int k = 0; k < 4; k++) {
        int idx = base + k;
        if (idx < n) {
            counts[idx] = run;
            run += v[k];
        }
    }
}

// XCD-sliced scatter. Destination space [0,NNZTOT) is split into NSLICE
// contiguous-by-row slices; slice(idx) = idx*NSLICE/NTOT (degrees uniform, so
// slices are ~equal destination ranges). Blocks with blockIdx%8==g process only
// slice slice_base+g; since blockIdx round-robins across the 8 XCDs, all writes
// to a slice come from ONE XCD's L2 -> full-line writebacks (no 8x write amp).
__global__ __launch_bounds__(256) void scatter_xcd_kernel(
        const int* __restrict__ a1r, const int* __restrict__ a1c,
        const float* __restrict__ a1v,
        const int* __restrict__ a2r, const int* __restrict__ a2c,
        const float* __restrict__ a2v,
        int* __restrict__ cursor,          // = rpe+1 (start offsets, mutated)
        int2* __restrict__ edges, int slice_base) {
    int group = blockIdx.x & 7;
    int chunk = blockIdx.x >> 3;
    int target = slice_base + group;
    int base = chunk * SC_CHUNK + threadIdx.x;
#pragma unroll
    for (int u = 0; u < SC_CHUNK / 256; u++) {
        int i = base + u * 256;
        if (i < NNZTOT) {
            int idx, srcj;
            const int* rc;
            const float* rv;
            if (i < 2 * NNZ1) {
                srcj = i;
                idx = ((i < NNZ1) ? 0 : N1) + __builtin_nontemporal_load(a1r + srcj);
                rc = a1c; rv = a1v;
            } else {
                srcj = i - 2 * NNZ1;
                idx = 2 * N1 + ((srcj < NNZ2) ? 0 : N2) + __builtin_nontemporal_load(a2r + srcj);
                rc = a2c; rv = a2v;
            }
            int sl = (int)((long)idx * NSLICE / NTOT);
            if (sl == target) {
                int   col = __builtin_nontemporal_load(rc + srcj);
                float val = __builtin_nontemporal_load(rv + srcj);
                int pos = atomicAdd(&cursor[idx], 1);
                edges[pos] = make_int2(col, __float_as_int(val));
            }
        }
    }
}

// ---------------- fused GCN row kernel ----------------
// Half-wave scheme: 2 edges in flight, 32 lanes x float4 per edge.
// Edge fetch is a uniform broadcast load per half-wave (no ds_bpermute).

__device__ __forceinline__ float4 row_gather(const int* __restrict__ rp,
                                             const int2* __restrict__ edges,
                                             int half, int sub,
                                             const float* __restrict__ xlo,
                                             const float* __restrict__ xhi,
                                             int nlo) {
    int s = rp[0];
    int e = rp[1];
    float4 acc = make_float4(0.f, 0.f, 0.f, 0.f);
    for (int k = s + half; k < e; k += 2) {
        int2 ed = edges[k];                 // same addr across half-wave: broadcast
        float v = __int_as_float(ed.y);
        const float* xb = (ed.x < nlo) ? xlo + (size_t)ed.x * FEATDIM
                                       : xhi + (size_t)(ed.x - nlo) * FEATDIM;
        float4 x4 = reinterpret_cast<const float4*>(xb)[sub];
        acc.x = fmaf(v, x4.x, acc.x);
        acc.y = fmaf(v, x4.y, acc.y);
        acc.z = fmaf(v, x4.z, acc.z);
        acc.w = fmaf(v, x4.w, acc.w);
    }
    return acc;
}

// one 64-lane wave per output row across BOTH graphs
__global__ __launch_bounds__(256) void fused_gcn2_kernel(
        const int* __restrict__ rpe,       // concatenated rowptr_ext
        const int2* __restrict__ edges,    // concatenated edge buffer
        const float* __restrict__ dE, const float* __restrict__ mE,
        const float* __restrict__ pE,
        float* __restrict__ out_d, float* __restrict__ g1med,
        float* __restrict__ out_p, float* __restrict__ g2med) {
    int gtid = blockIdx.x * blockDim.x + threadIdx.x;
    int w    = gtid >> 6;
    int lane = gtid & 63;
    int half = lane >> 5;
    int sub  = lane & 31;
    if (w >= N1 + N2) return;

    const float *xlo, *xhi;
    const int *rpA, *rpB;
    float* dst;
    int nlo;
    if (w < N1) {
        xlo = dE; xhi = mE; nlo = DIAGNUM;
        rpA = rpe + w;
        rpB = rpe + N1 + w;
        dst = (w < DIAGNUM) ? out_d + (size_t)w * FEATDIM
                            : g1med + (size_t)(w - DIAGNUM) * FEATDIM;
    } else {
        int r = w - N1;
        xlo = pE; xhi = mE; nlo = PRONUM;
        rpA = rpe + 2 * N1 + r;
        rpB = rpe + 2 * N1 + N2 + r;
        dst = (r < PRONUM) ? out_p + (size_t)r * FEATDIM
                           : g2med + (size_t)(r - PRONUM) * FEATDIM;
    }

    float4 sA = row_gather(rpA, edges, half, sub, xlo, xhi, nlo);
    float4 sB = row_gather(rpB, edges, half, sub, xlo, xhi, nlo);

    float4 res;
    res.x = 2.f * (fmaxf(sA.x + __shfl_xor(sA.x, 32), 0.f) +
                   fmaxf(sB.x + __shfl_xor(sB.x, 32), 0.f));
    res.y = 2.f * (fmaxf(sA.y + __shfl_xor(sA.y, 32), 0.f) +
                   fmaxf(sB.y + __shfl_xor(sB.y, 32), 0.f));
    res.z = 2.f * (fmaxf(sA.z + __shfl_xor(sA.z, 32), 0.f) +
                   fmaxf(sB.z + __shfl_xor(sB.z, 32), 0.f));
    res.w = 2.f * (fmaxf(sA.w + __shfl_xor(sA.w, 32), 0.f) +
                   fmaxf(sB.w + __shfl_xor(sB.w, 32), 0.f));

    if (half == 0) {
        reinterpret_cast<float4*>(dst)[sub] = res;
    }
}

// out_m = t*g1med + (1-t)*g2med
__global__ void combine_med_kernel(const float* __restrict__ g1med,
                                   const float* __restrict__ g2med,
                                   const float* __restrict__ inter,
                                   float* __restrict__ outm, long total_elems) {
    long i = ((long)blockIdx.x * blockDim.x + threadIdx.x) * 4;
    if (i >= total_elems) return;
    float t = *inter;
    float4 a = *reinterpret_cast<const float4*>(g1med + i);
    float4 b = *reinterpret_cast<const float4*>(g2med + i);
    float4 v;
    v.x = t * a.x + (1.0f - t) * b.x;
    v.y = t * a.y + (1.0f - t) * b.y;
    v.z = t * a.z + (1.0f - t) * b.z;
    v.w = t * a.w + (1.0f - t) * b.w;
    *reinterpret_cast<float4*>(outm + i) = v;
}

// ---------------- host orchestration ----------------

extern "C" void kernel_launch(void* const* d_in, const int* in_sizes, int n_in,
                              void* d_out, int out_size, void* d_ws, size_t ws_size,
                              hipStream_t stream) {
    const int*   a1r = (const int*)d_in[0];
    const int*   a1c = (const int*)d_in[1];
    const float* a1v = (const float*)d_in[2];
    const int*   a2r = (const int*)d_in[3];
    const int*   a2c = (const int*)d_in[4];
    const float* a2v = (const float*)d_in[5];
    const float* dE  = (const float*)d_in[6];
    const float* mE  = (const float*)d_in[7];
    const float* pE  = (const float*)d_in[8];
    const float* inter = (const float*)d_in[9];

    float* out   = (float*)d_out;
    float* out_m = out;                               // 20000*128
    float* out_d = out + (size_t)MEDNUM * FEATDIM;    // 50000*128
    float* out_p = out_d + (size_t)DIAGNUM * FEATDIM; // 40000*128

    // ws layout
    char* ws = (char*)d_ws;
    float* g1med = (float*)ws;      ws += (size_t)MEDNUM * FEATDIM * 4;   // 10.24 MB
    float* g2med = (float*)ws;      ws += (size_t)MEDNUM * FEATDIM * 4;   // 10.24 MB
    int2*  edges = (int2*)ws;       ws += (size_t)NNZTOT * 8;             // 33.28 MB
    int*   rpe   = (int*)ws;        ws += (size_t)(NTOT + 1) * 4;         // 1.04 MB
    int*   partials = (int*)ws;     ws += 256 * 4;

    const int BLK = 256;
    int nchunks = (NTOT + 1023) / 1024;   // 254

    // rpe[0] = 0, counts (rpe+1) = 0
    hipMemsetAsync(rpe, 0, (size_t)(NTOT + 1) * sizeof(int), stream);
    hist4_kernel<<<(NNZTOT + BLK - 1) / BLK, BLK, 0, stream>>>(a1r, a2r, rpe + 1);
    scan_reduce_kernel<<<nchunks, BLK, 0, stream>>>(rpe + 1, NTOT, partials);
    scan_mid_kernel<<<1, BLK, 0, stream>>>(partials, nchunks);
    scan_apply_kernel<<<nchunks, BLK, 0, stream>>>(rpe + 1, NTOT, partials);

    // XCD-sliced scatter: 2 passes x 8 XCD-groups
    int sc_chunks = (NNZTOT + SC_CHUNK - 1) / SC_CHUNK;   // 2032
    int sc_grid = sc_chunks * 8;                          // 16256
    scatter_xcd_kernel<<<sc_grid, BLK, 0, stream>>>(a1r, a1c, a1v, a2r, a2c, a2v,
                                                    rpe + 1, edges, 0);
    scatter_xcd_kernel<<<sc_grid, BLK, 0, stream>>>(a1r, a1c, a1v, a2r, a2c, a2v,
                                                    rpe + 1, edges, 8);

    // fused GCN over both graphs: one wave per row, 4 rows per block
    int nrows = N1 + N2;   // 130000
    fused_gcn2_kernel<<<(nrows + 3) / 4, BLK, 0, stream>>>(
        rpe, edges, dE, mE, pE, out_d, g1med, out_p, g2med);

    long totm = (long)MEDNUM * FEATDIM;
    combine_med_kernel<<<(int)((totm / 4 + BLK - 1) / BLK), BLK, 0, stream>>>(
        g1med, g2med, inter, out_m, totm);
}